// Round 12
// baseline (587.753 us; speedup 1.0000x reference)
//
#include <hip/hip_runtime.h>

typedef __bf16 bf16;
typedef __bf16 bf16x8 __attribute__((ext_vector_type(8)));
typedef __bf16 bf16x4 __attribute__((ext_vector_type(4)));
typedef float  f32x4  __attribute__((ext_vector_type(4)));

__device__ __forceinline__ f32x4 mfma16(bf16x8 a, bf16x8 b, f32x4 c) {
    return __builtin_amdgcn_mfma_f32_16x16x32_bf16(a, b, c, 0, 0, 0);
}

__device__ __forceinline__ void gll16(const bf16* g, bf16* l) {
    __builtin_amdgcn_global_load_lds(
        (const __attribute__((address_space(1))) void*)g,
        (__attribute__((address_space(3))) void*)l, 16, 0, 0);
}

#define SCHED_FENCE() __builtin_amdgcn_sched_barrier(0)

// ---------------- K0: weight repack (BqT scaled+deinterleaved, kvWT, projT) ----------------
__global__ __launch_bounds__(256) void prep_weights(
    const float* __restrict__ qkv_w, const float* __restrict__ qkv_b,
    const float* __restrict__ proj_w,
    bf16* __restrict__ BqT, bf16* __restrict__ kvWT, bf16* __restrict__ projWT,
    float* __restrict__ bkv)
{
    int i = blockIdx.x * 256 + threadIdx.x;
    if (i < 262144) {
        int c_ = i >> 9, k = i & 511;
        int c = (c_ >> 6) * 192 + (c_ & 63) * 3;
        BqT[i] = (bf16)(qkv_w[k * 1536 + c] * 0.125f);
        return;
    }
    i -= 262144;
    if (i < 131072) {
        int c2 = i >> 9, k = i & 511;
        int t = c2 >> 7, kk = (c2 >> 6) & 1, e = c2 & 63;
        int c = t * 192 + e * 3 + 1 + kk;
        kvWT[i] = (bf16)(qkv_w[k * 1536 + c]);
        return;
    }
    i -= 131072;
    if (i < 262144) {
        int c_ = i >> 9, k = i & 511;
        projWT[i] = (bf16)(proj_w[k * 512 + c_]);
        return;
    }
    i -= 262144;
    if (i < 256) {
        int t = i >> 7, kk = (i >> 6) & 1, e = i & 63;
        bkv[i] = qkv_b[t * 192 + e * 3 + 1 + kk];
    }
}

// ---------------- K0b: R = pe_w @ Wq_scaled [3][512], bq2 — block-parallel reduce ----------------
__global__ __launch_bounds__(256) void prep_r2(
    const float* __restrict__ qkv_w, const float* __restrict__ qkv_b,
    const float* __restrict__ pe_w, const float* __restrict__ pe_b,
    float* __restrict__ R, float* __restrict__ bq2)
{
    const int c = blockIdx.x;            // 512
    const int tid = threadIdx.x;
    const int qc = (c >> 6) * 192 + (c & 63) * 3;
    float p0 = 0.f, p1 = 0.f, p2 = 0.f, p3 = 0.f;
    for (int k = tid; k < 512; k += 256) {
        float wv = qkv_w[(size_t)k * 1536 + qc];
        p0 += wv * pe_w[k];
        p1 += wv * pe_w[512 + k];
        p2 += wv * pe_w[1024 + k];
        p3 += wv * pe_b[k];
    }
    #pragma unroll
    for (int m = 1; m < 64; m <<= 1) {
        p0 += __shfl_xor(p0, m);
        p1 += __shfl_xor(p1, m);
        p2 += __shfl_xor(p2, m);
        p3 += __shfl_xor(p3, m);
    }
    __shared__ float red[4][4];
    int w = tid >> 6;
    if ((tid & 63) == 0) { red[w][0] = p0; red[w][1] = p1; red[w][2] = p2; red[w][3] = p3; }
    __syncthreads();
    if (tid == 0) {
        float s0 = red[0][0] + red[1][0] + red[2][0] + red[3][0];
        float s1 = red[0][1] + red[1][1] + red[2][1] + red[3][1];
        float s2 = red[0][2] + red[1][2] + red[2][2] + red[3][2];
        float s3 = red[0][3] + red[1][3] + red[2][3] + red[3][3];
        R[0 * 512 + c] = 0.125f * s0;
        R[1 * 512 + c] = 0.125f * s1;
        R[2 * 512 + c] = 0.125f * s2;
        bq2[c] = 0.125f * (qkv_b[qc] + s3);
    }
}

// ---------------- K0c: rel[t][3] = pos - ball mean ----------------
__global__ __launch_bounds__(64) void relprep(const float* __restrict__ pos,
                                              float* __restrict__ rel)
{
    const int t = blockIdx.x * 64 + threadIdx.x;
    float p0 = pos[(size_t)t * 3 + 0];
    float p1 = pos[(size_t)t * 3 + 1];
    float p2 = pos[(size_t)t * 3 + 2];
    float s0 = p0, s1 = p1, s2 = p2;
    #pragma unroll
    for (int m = 1; m < 64; m <<= 1) {
        s0 += __shfl_xor(s0, m);
        s1 += __shfl_xor(s1, m);
        s2 += __shfl_xor(s2, m);
    }
    rel[(size_t)t * 3 + 0] = p0 - s0 * (1.0f / 64.0f);
    rel[(size_t)t * 3 + 1] = p1 - s1 * (1.0f / 64.0f);
    rel[(size_t)t * 3 + 2] = p2 - s2 * (1.0f / 64.0f);
}

// ---------------- K1: Q GEMM — full-N 64x512, BK=32, dbuf A+B, 1 barrier/iter ----------------
// Pipeline waits are REGISTER-DEPENDENCY driven: ds_write A(t+1) makes the compiler
// emit a vmcnt that retires everything older, including B(t)'s gll16 (issued one
// iter earlier) — no hand-counted vmcnt, no race-by-miscount. ~5 VMEM stay in
// flight across each barrier. LDS 72 KB -> 2 blocks/CU (16 waves).
__global__ __launch_bounds__(512, 4) void qgemm7(
    const float* __restrict__ X, const bf16* __restrict__ Bt,
    const float* __restrict__ rel, const float* __restrict__ R,
    const float* __restrict__ bq2, bf16* __restrict__ Qout)
{
    const int row0 = blockIdx.x * 64;
    const int tid = threadIdx.x;
    const int w = tid >> 6, l = tid & 63;
    const int l15 = l & 15, lg = l >> 4;

    __shared__ __align__(16) bf16 As[2][2048];   // 64 rows x 32 k, swizzled, 2 bufs
    __shared__ __align__(16) bf16 Bs[2][16384];  // 512 cols x 32 k, swizzled, 2 bufs

    f32x4 acc[4][4] = {};

    // A staging: thread -> row=tid>>3, j=tid&7 covers k [j*4, j*4+4)
    const int arow = tid >> 3;
    const int aj = tid & 7;
    const int awpos = arow * 32 + (((aj >> 1) ^ (arow & 3)) << 3) + (aj & 1) * 4;
    const float* xp = X + (size_t)(row0 + arow) * 512 + aj * 4;

    // B staging: chunk c = w*4+jj (16 cols x 32k each); lane: col=l>>2, kslot=l&3
    const int brow = l >> 2;
    const int bkoff = (((l & 3) ^ ((l >> 2) & 3)) << 3);

    float4 va[2];

    // prologue: B(0), A(0) write, A(1) -> va[1]
    #pragma unroll
    for (int jj = 0; jj < 4; ++jj) {
        int c = w * 4 + jj;
        gll16(Bt + (size_t)(c * 16 + brow) * 512 + bkoff, &Bs[0][c * 512]);
    }
    {
        float4 v0 = *(const float4*)xp;
        bf16x4 bv = { (bf16)v0.x, (bf16)v0.y, (bf16)v0.z, (bf16)v0.w };
        *(bf16x4*)&As[0][awpos] = bv;            // auto-wait drains B(0) (older)
    }
    va[1] = *(const float4*)(xp + 32);
    asm volatile("s_waitcnt lgkmcnt(0)" ::: "memory");
    __builtin_amdgcn_s_barrier();

    #pragma unroll 2
    for (int t = 0; t < 16; ++t) {
        SCHED_FENCE();
        if (t < 15) {
            #pragma unroll
            for (int jj = 0; jj < 4; ++jj) {
                int c = w * 4 + jj;
                gll16(Bt + (size_t)(c * 16 + brow) * 512 + (t + 1) * 32 + bkoff,
                      &Bs[(t + 1) & 1][c * 512]);
            }
            if (t < 14) va[t & 1] = *(const float4*)(xp + (t + 2) * 32);
            SCHED_FENCE();
            float4 v = va[(t + 1) & 1];
            bf16x4 bv = { (bf16)v.x, (bf16)v.y, (bf16)v.z, (bf16)v.w };
            *(bf16x4*)&As[(t + 1) & 1][awpos] = bv;  // auto vmcnt: A(t+1) ready => B(t) landed
            SCHED_FENCE();
        } else {
            asm volatile("s_waitcnt vmcnt(0)" ::: "memory");
            __builtin_amdgcn_s_barrier();
            SCHED_FENCE();
        }

        const bf16* Ac = As[t & 1];
        const bf16* Bc = Bs[t & 1];
        bf16x8 a[4], b[4];
        #pragma unroll
        for (int mi = 0; mi < 4; ++mi) {
            int r = mi * 16 + l15;
            a[mi] = *(const bf16x8*)&Ac[r * 32 + ((lg ^ (r & 3)) << 3)];
        }
        #pragma unroll
        for (int ni = 0; ni < 4; ++ni) {
            int r = w * 64 + ni * 16 + l15;
            b[ni] = *(const bf16x8*)&Bc[r * 32 + ((lg ^ (r & 3)) << 3)];
        }
        #pragma unroll
        for (int mi = 0; mi < 4; ++mi)
            #pragma unroll
            for (int ni = 0; ni < 4; ++ni)
                acc[mi][ni] = mfma16(a[mi], b[ni], acc[mi][ni]);

        SCHED_FENCE();
        asm volatile("s_waitcnt lgkmcnt(0)" ::: "memory");
        __builtin_amdgcn_s_barrier();
    }
    SCHED_FENCE();

    // epilogue constants through dead LDS (As = 8 KB = 512 float4)
    {
        float4 cp;
        cp.x = bq2[tid];
        cp.y = R[tid];
        cp.z = R[512 + tid];
        cp.w = R[1024 + tid];
        ((float4*)As)[tid] = cp;
    }
    if (tid < 64) {
        ((float*)Bs)[tid * 3 + 0] = rel[(size_t)(row0 + tid) * 3 + 0];
        ((float*)Bs)[tid * 3 + 1] = rel[(size_t)(row0 + tid) * 3 + 1];
        ((float*)Bs)[tid * 3 + 2] = rel[(size_t)(row0 + tid) * 3 + 2];
    }
    __syncthreads();

    #pragma unroll
    for (int mi = 0; mi < 4; ++mi) {
        float rl[4][3];
        #pragma unroll
        for (int r = 0; r < 4; ++r) {
            int rowL = mi * 16 + lg * 4 + r;
            rl[r][0] = ((const float*)Bs)[rowL * 3 + 0];
            rl[r][1] = ((const float*)Bs)[rowL * 3 + 1];
            rl[r][2] = ((const float*)Bs)[rowL * 3 + 2];
        }
        #pragma unroll
        for (int ni = 0; ni < 4; ++ni) {
            int col = w * 64 + ni * 16 + l15;
            float4 cp = ((const float4*)As)[col];
            #pragma unroll
            for (int r = 0; r < 4; ++r) {
                int rowL = mi * 16 + lg * 4 + r;
                float vv = acc[mi][ni][r] + cp.x
                         + rl[r][0] * cp.y + rl[r][1] * cp.z + rl[r][2] * cp.w;
                Qout[(size_t)(row0 + rowL) * 512 + col] = (bf16)vv;
            }
        }
    }
}

// ---------------- K4: proj GEMM — same full-N dbuf pipeline, A bf16 reg-staged ----------------
__global__ __launch_bounds__(512, 4) void pgemm7(
    const bf16* __restrict__ A, const bf16* __restrict__ Bt,
    const float* __restrict__ bias, float* __restrict__ out)
{
    const int row0 = blockIdx.x * 64;
    const int tid = threadIdx.x;
    const int w = tid >> 6, l = tid & 63;
    const int l15 = l & 15, lg = l >> 4;

    __shared__ __align__(16) bf16 As[2][2048];
    __shared__ __align__(16) bf16 Bs[2][16384];

    f32x4 acc[4][4] = {};

    const int arow = tid >> 3;
    const int aj = tid & 7;
    const int awpos = arow * 32 + (((aj >> 1) ^ (arow & 3)) << 3) + (aj & 1) * 4;
    const bf16* ap = A + (size_t)(row0 + arow) * 512 + aj * 4;

    const int brow = l >> 2;
    const int bkoff = (((l & 3) ^ ((l >> 2) & 3)) << 3);

    bf16x4 va[2];

    #pragma unroll
    for (int jj = 0; jj < 4; ++jj) {
        int c = w * 4 + jj;
        gll16(Bt + (size_t)(c * 16 + brow) * 512 + bkoff, &Bs[0][c * 512]);
    }
    {
        bf16x4 v0 = *(const bf16x4*)ap;
        *(bf16x4*)&As[0][awpos] = v0;
    }
    va[1] = *(const bf16x4*)(ap + 32);
    asm volatile("s_waitcnt lgkmcnt(0)" ::: "memory");
    __builtin_amdgcn_s_barrier();

    #pragma unroll 2
    for (int t = 0; t < 16; ++t) {
        SCHED_FENCE();
        if (t < 15) {
            #pragma unroll
            for (int jj = 0; jj < 4; ++jj) {
                int c = w * 4 + jj;
                gll16(Bt + (size_t)(c * 16 + brow) * 512 + (t + 1) * 32 + bkoff,
                      &Bs[(t + 1) & 1][c * 512]);
            }
            if (t < 14) va[t & 1] = *(const bf16x4*)(ap + (t + 2) * 32);
            SCHED_FENCE();
            *(bf16x4*)&As[(t + 1) & 1][awpos] = va[(t + 1) & 1];
            SCHED_FENCE();
        } else {
            asm volatile("s_waitcnt vmcnt(0)" ::: "memory");
            __builtin_amdgcn_s_barrier();
            SCHED_FENCE();
        }

        const bf16* Ac = As[t & 1];
        const bf16* Bc = Bs[t & 1];
        bf16x8 a[4], b[4];
        #pragma unroll
        for (int mi = 0; mi < 4; ++mi) {
            int r = mi * 16 + l15;
            a[mi] = *(const bf16x8*)&Ac[r * 32 + ((lg ^ (r & 3)) << 3)];
        }
        #pragma unroll
        for (int ni = 0; ni < 4; ++ni) {
            int r = w * 64 + ni * 16 + l15;
            b[ni] = *(const bf16x8*)&Bc[r * 32 + ((lg ^ (r & 3)) << 3)];
        }
        #pragma unroll
        for (int mi = 0; mi < 4; ++mi)
            #pragma unroll
            for (int ni = 0; ni < 4; ++ni)
                acc[mi][ni] = mfma16(a[mi], b[ni], acc[mi][ni]);

        SCHED_FENCE();
        asm volatile("s_waitcnt lgkmcnt(0)" ::: "memory");
        __builtin_amdgcn_s_barrier();
    }
    SCHED_FENCE();

    #pragma unroll
    for (int ni = 0; ni < 4; ++ni) {
        int col = w * 64 + ni * 16 + l15;
        float bv = bias[col];
        #pragma unroll
        for (int mi = 0; mi < 4; ++mi) {
            int rowL = mi * 16 + lg * 4;
            #pragma unroll
            for (int r = 0; r < 4; ++r)
                out[(size_t)(row0 + rowL + r) * 512 + col] = acc[mi][ni][r] + bv;
        }
    }
}

// ---------------- K2: k_sel / v_selT (x' recomputed inline for 1024 tokens) ----------------
__global__ __launch_bounds__(256) void kv_proj2(
    const float* __restrict__ x, const float* __restrict__ rel,
    const float* __restrict__ pe_w, const float* __restrict__ pe_b,
    const bf16* __restrict__ kvWT, const float* __restrict__ bkv,
    bf16* __restrict__ ksel, bf16* __restrict__ vselT)
{
    const int bid = blockIdx.x;
    const int b = bid >> 9;
    const int ball = (bid >> 6) & 7;
    const int m2 = bid & 63;
    const size_t tok = (size_t)b * 65536 + ball * 64 + m2;
    const int tid = threadIdx.x;

    __shared__ __align__(16) bf16 xrow[512];
    __shared__ float relt[3];
    if (tid < 3) relt[tid] = rel[tok * 3 + tid];
    __syncthreads();
    for (int k = tid; k < 512; k += 256) {
        float v = x[tok * 512 + k] + relt[0] * pe_w[k] + relt[1] * pe_w[512 + k]
                + relt[2] * pe_w[1024 + k] + pe_b[k];
        xrow[k] = (bf16)v;
    }
    __syncthreads();

    float acc = 0.f;
    const bf16* wrp = kvWT + (size_t)tid * 512;
    #pragma unroll 8
    for (int k = 0; k < 512; k += 8) {
        bf16x8 wv = *(const bf16x8*)(wrp + k);
        bf16x8 xv = *(const bf16x8*)(&xrow[k]);
        #pragma unroll
        for (int j = 0; j < 8; ++j) acc += (float)xv[j] * (float)wv[j];
    }
    acc += bkv[tid];
    int t = tid >> 7, kk = (tid >> 6) & 1, e = tid & 63;
    if (kk == 0)
        ksel[((size_t)(b * 8 + ball) * 128 + t * 64 + m2) * 64 + e] = (bf16)acc;
    else
        vselT[((size_t)(b * 8 + ball) * 64 + e) * 128 + t * 64 + m2] = (bf16)acc;
}

// ---------------- K3: attention, 16 q-tiles per block (K/V staged once) ----------------
__global__ __launch_bounds__(256) void attn16(
    const bf16* __restrict__ q, const bf16* __restrict__ ksel,
    const bf16* __restrict__ vselT, bf16* __restrict__ attno)
{
    const int bid = blockIdx.x;      // 1024 = 16 bh * 64 qgroups
    const int qg = bid & 63;
    const int bh = bid >> 6;
    const int b = bh >> 3;
    const int h = bh & 7;
    const int tid = threadIdx.x;
    const int w = tid >> 6;
    const int l = tid & 63;
    const int l15 = l & 15, lg = l >> 4;

    __shared__ __align__(16) bf16 Ks[128][72];
    __shared__ __align__(16) bf16 Vt[64][136];
    __shared__ __align__(16) bf16 Pl[4][16][136];

    const bf16* kg = ksel + (size_t)(b * 8 + h) * 128 * 64;
    #pragma unroll
    for (int it = 0; it < 4; ++it) {
        int i = it * 256 + tid;
        int r = i >> 3, c8 = (i & 7) * 8;
        *(bf16x8*)&Ks[r][c8] = *(const bf16x8*)(kg + r * 64 + c8);
    }
    const bf16* vg = vselT + (size_t)(b * 8 + h) * 64 * 128;
    #pragma unroll
    for (int it = 0; it < 4; ++it) {
        int i = it * 256 + tid;
        int r = i >> 4, c8 = (i & 15) * 8;
        *(bf16x8*)&Vt[r][c8] = *(const bf16x8*)(vg + r * 128 + c8);
    }
    __syncthreads();

    for (int qi = 0; qi < 16; ++qi) {
        const int qt = qg * 16 + qi;
        const size_t tokq = (size_t)b * 65536 + (size_t)qt * 64 + w * 16 + l15;
        const bf16* qp = q + tokq * 512 + h * 64 + lg * 8;
        bf16x8 qa0 = *(const bf16x8*)qp;
        bf16x8 qa1 = *(const bf16x8*)(qp + 32);

        f32x4 s[8];
        #pragma unroll
        for (int kt = 0; kt < 8; ++kt) {
            f32x4 a0 = {0.f, 0.f, 0.f, 0.f};
            a0 = mfma16(qa0, *(const bf16x8*)&Ks[kt * 16 + l15][lg * 8], a0);
            a0 = mfma16(qa1, *(const bf16x8*)&Ks[kt * 16 + l15][32 + lg * 8], a0);
            s[kt] = a0;
        }

        #pragma unroll
        for (int r = 0; r < 4; ++r) {
            float mx = s[0][r];
            #pragma unroll
            for (int kt = 1; kt < 8; ++kt) mx = fmaxf(mx, s[kt][r]);
            mx = fmaxf(mx, __shfl_xor(mx, 1));
            mx = fmaxf(mx, __shfl_xor(mx, 2));
            mx = fmaxf(mx, __shfl_xor(mx, 4));
            mx = fmaxf(mx, __shfl_xor(mx, 8));
            float sum = 0.f;
            #pragma unroll
            for (int kt = 0; kt < 8; ++kt) {
                float p = __expf(s[kt][r] - mx);
                s[kt][r] = p;
                sum += p;
            }
            sum += __shfl_xor(sum, 1);
            sum += __shfl_xor(sum, 2);
            sum += __shfl_xor(sum, 4);
            sum += __shfl_xor(sum, 8);
            float inv = 1.0f / sum;
            int prow = lg * 4 + r;
            #pragma unroll
            for (int kt = 0; kt < 8; ++kt)
                Pl[w][prow][kt * 16 + l15] = (bf16)(s[kt][r] * inv);
        }

        f32x4 o[4] = { {0,0,0,0}, {0,0,0,0}, {0,0,0,0}, {0,0,0,0} };
        #pragma unroll
        for (int kc = 0; kc < 4; ++kc) {
            bf16x8 pa = *(const bf16x8*)&Pl[w][l15][kc * 32 + lg * 8];
            #pragma unroll
            for (int et = 0; et < 4; ++et)
                o[et] = mfma16(pa, *(const bf16x8*)&Vt[et * 16 + l15][kc * 32 + lg * 8], o[et]);
        }

        #pragma unroll
        for (int et = 0; et < 4; ++et)
            #pragma unroll
            for (int r = 0; r < 4; ++r)
                Pl[w][lg * 4 + r][et * 16 + l15] = (bf16)(o[et][r]);

        __syncthreads();
        {
            int rowg = tid >> 2;
            int w2 = rowg >> 4, lr = rowg & 15;
            int chunk = tid & 3;
            const size_t tok = (size_t)b * 65536 + (size_t)qt * 64 + rowg;
            bf16* gp = attno + tok * 512 + h * 64 + chunk * 16;
            const bf16* lp = &Pl[w2][lr][chunk * 16];
            *(bf16x8*)(gp + 0) = *(const bf16x8*)(lp + 0);
            *(bf16x8*)(gp + 8) = *(const bf16x8*)(lp + 8);
        }
        __syncthreads();
    }
}

extern "C" void kernel_launch(void* const* d_in, const int* in_sizes, int n_in,
                              void* d_out, int out_size, void* d_ws, size_t ws_size,
                              hipStream_t stream) {
    (void)in_sizes; (void)n_in; (void)out_size; (void)ws_size;
    const float* x      = (const float*)d_in[0];
    const float* pos    = (const float*)d_in[1];
    const float* qkv_w  = (const float*)d_in[2];
    const float* qkv_b  = (const float*)d_in[3];
    const float* proj_w = (const float*)d_in[4];
    const float* proj_b = (const float*)d_in[5];
    const float* pe_w   = (const float*)d_in[6];
    const float* pe_b   = (const float*)d_in[7];

    char* ws = (char*)d_ws;
    bf16*  Q     = (bf16*)(ws);                          // 134217728
    bf16*  Z     = (bf16*)(ws + 134217728);              // 134217728 (attn out)
    bf16*  BqT   = (bf16*)(ws + 268435456);              // 524288
    bf16*  PjT   = (bf16*)(ws + 268959744);              // 524288
    bf16*  kvWT  = (bf16*)(ws + 269484032);              // 262144
    bf16*  ksel  = (bf16*)(ws + 269746176);              // 262144
    bf16*  vselT = (bf16*)(ws + 270008320);              // 262144
    float* rel   = (float*)(ws + 270270464);             // 1572864
    float* R     = (float*)(ws + 271843328);             // 6144
    float* bq2   = (float*)(ws + 271849472);             // 2048
    float* bkv   = (float*)(ws + 271851520);             // 1024

    prep_weights<<<2561, 256, 0, stream>>>(qkv_w, qkv_b, proj_w, BqT, kvWT, PjT, bkv);
    prep_r2<<<512, 256, 0, stream>>>(qkv_w, qkv_b, pe_w, pe_b, R, bq2);
    relprep<<<2048, 64, 0, stream>>>(pos, rel);
    qgemm7<<<2048, 512, 0, stream>>>(x, BqT, rel, R, bq2, Q);
    kv_proj2<<<1024, 256, 0, stream>>>(x, rel, pe_w, pe_b, kvWT, bkv, ksel, vselT);
    attn16<<<1024, 256, 0, stream>>>(Q, ksel, vselT, Z);
    pgemm7<<<2048, 512, 0, stream>>>(Z, PjT, proj_b, (float*)d_out);
}

// Round 13
// 429.566 us; speedup vs baseline: 1.3682x; 1.3682x over previous
//
#include <hip/hip_runtime.h>

typedef __bf16 bf16;
typedef __bf16 bf16x8 __attribute__((ext_vector_type(8)));
typedef __bf16 bf16x4 __attribute__((ext_vector_type(4)));
typedef float  f32x4  __attribute__((ext_vector_type(4)));

__device__ __forceinline__ f32x4 mfma16(bf16x8 a, bf16x8 b, f32x4 c) {
    return __builtin_amdgcn_mfma_f32_16x16x32_bf16(a, b, c, 0, 0, 0);
}

__device__ __forceinline__ void gll16(const bf16* g, bf16* l) {
    __builtin_amdgcn_global_load_lds(
        (const __attribute__((address_space(1))) void*)g,
        (__attribute__((address_space(3))) void*)l, 16, 0, 0);
}

#define SCHED_FENCE() __builtin_amdgcn_sched_barrier(0)

// ---------------- K0: weight repack (BqT scaled+deinterleaved, kvWT, projT) ----------------
__global__ __launch_bounds__(256) void prep_weights(
    const float* __restrict__ qkv_w, const float* __restrict__ qkv_b,
    const float* __restrict__ proj_w,
    bf16* __restrict__ BqT, bf16* __restrict__ kvWT, bf16* __restrict__ projWT,
    float* __restrict__ bkv)
{
    int i = blockIdx.x * 256 + threadIdx.x;
    if (i < 262144) {
        int c_ = i >> 9, k = i & 511;
        int c = (c_ >> 6) * 192 + (c_ & 63) * 3;
        BqT[i] = (bf16)(qkv_w[k * 1536 + c] * 0.125f);
        return;
    }
    i -= 262144;
    if (i < 131072) {
        int c2 = i >> 9, k = i & 511;
        int t = c2 >> 7, kk = (c2 >> 6) & 1, e = c2 & 63;
        int c = t * 192 + e * 3 + 1 + kk;
        kvWT[i] = (bf16)(qkv_w[k * 1536 + c]);
        return;
    }
    i -= 131072;
    if (i < 262144) {
        int c_ = i >> 9, k = i & 511;
        projWT[i] = (bf16)(proj_w[k * 512 + c_]);
        return;
    }
    i -= 262144;
    if (i < 256) {
        int t = i >> 7, kk = (i >> 6) & 1, e = i & 63;
        bkv[i] = qkv_b[t * 192 + e * 3 + 1 + kk];
    }
}

// ---------------- K0b: R = pe_w @ Wq_scaled [3][512], bq2 — block-parallel reduce ----------------
__global__ __launch_bounds__(256) void prep_r2(
    const float* __restrict__ qkv_w, const float* __restrict__ qkv_b,
    const float* __restrict__ pe_w, const float* __restrict__ pe_b,
    float* __restrict__ R, float* __restrict__ bq2)
{
    const int c = blockIdx.x;            // 512
    const int tid = threadIdx.x;
    const int qc = (c >> 6) * 192 + (c & 63) * 3;
    float p0 = 0.f, p1 = 0.f, p2 = 0.f, p3 = 0.f;
    for (int k = tid; k < 512; k += 256) {
        float wv = qkv_w[(size_t)k * 1536 + qc];
        p0 += wv * pe_w[k];
        p1 += wv * pe_w[512 + k];
        p2 += wv * pe_w[1024 + k];
        p3 += wv * pe_b[k];
    }
    #pragma unroll
    for (int m = 1; m < 64; m <<= 1) {
        p0 += __shfl_xor(p0, m);
        p1 += __shfl_xor(p1, m);
        p2 += __shfl_xor(p2, m);
        p3 += __shfl_xor(p3, m);
    }
    __shared__ float red[4][4];
    int w = tid >> 6;
    if ((tid & 63) == 0) { red[w][0] = p0; red[w][1] = p1; red[w][2] = p2; red[w][3] = p3; }
    __syncthreads();
    if (tid == 0) {
        float s0 = red[0][0] + red[1][0] + red[2][0] + red[3][0];
        float s1 = red[0][1] + red[1][1] + red[2][1] + red[3][1];
        float s2 = red[0][2] + red[1][2] + red[2][2] + red[3][2];
        float s3 = red[0][3] + red[1][3] + red[2][3] + red[3][3];
        R[0 * 512 + c] = 0.125f * s0;
        R[1 * 512 + c] = 0.125f * s1;
        R[2 * 512 + c] = 0.125f * s2;
        bq2[c] = 0.125f * (qkv_b[qc] + s3);
    }
}

// ---------------- K0c: rel[t][3] = pos - ball mean ----------------
__global__ __launch_bounds__(64) void relprep(const float* __restrict__ pos,
                                              float* __restrict__ rel)
{
    const int t = blockIdx.x * 64 + threadIdx.x;
    float p0 = pos[(size_t)t * 3 + 0];
    float p1 = pos[(size_t)t * 3 + 1];
    float p2 = pos[(size_t)t * 3 + 2];
    float s0 = p0, s1 = p1, s2 = p2;
    #pragma unroll
    for (int m = 1; m < 64; m <<= 1) {
        s0 += __shfl_xor(s0, m);
        s1 += __shfl_xor(s1, m);
        s2 += __shfl_xor(s2, m);
    }
    rel[(size_t)t * 3 + 0] = p0 - s0 * (1.0f / 64.0f);
    rel[(size_t)t * 3 + 1] = p1 - s1 * (1.0f / 64.0f);
    rel[(size_t)t * 3 + 2] = p2 - s2 * (1.0f / 64.0f);
}

// ---------------- K1: Q = bf16(x') @ BqT^T — FULL-N block (64 rows x 512 cols) ----------------
// 8 waves; wave w owns cols [w*64, w*64+64). A read ONCE per row; B via gll16 (L2-hot).
__global__ __launch_bounds__(512) void qgemm6(
    const float* __restrict__ X, const bf16* __restrict__ Bt,
    const float* __restrict__ rel, const float* __restrict__ R,
    const float* __restrict__ bq2, bf16* __restrict__ Qout)
{
    const int row0 = blockIdx.x * 64;
    const int tid = threadIdx.x;
    const int w = tid >> 6, l = tid & 63;
    const int l15 = l & 15, lg = l >> 4;

    __shared__ __align__(16) bf16 As[4096];      // 64 rows x 64 k (swizzled)
    __shared__ __align__(16) bf16 Bs[32768];     // 512 cols x 64 k (swizzled)

    f32x4 acc[4][4] = {};

    const int arow = tid >> 3;
    const int aslot = ((tid & 7) ^ (arow & 7)) << 3;
    const float* xrow_p = X + (size_t)(row0 + arow) * 512 + (tid & 7) * 8;

    const int bsrow = l >> 3;
    const int bscol = (((l & 7) ^ (l >> 3)) << 3);

    float4 va0 = *(const float4*)xrow_p;
    float4 va1 = *(const float4*)(xrow_p + 4);

    for (int ki = 0; ki < 8; ++ki) {
        int ks = ki * 64;
        {
            bf16x8 bv = { (bf16)va0.x, (bf16)va0.y, (bf16)va0.z, (bf16)va0.w,
                          (bf16)va1.x, (bf16)va1.y, (bf16)va1.z, (bf16)va1.w };
            *(bf16x8*)&As[arow * 64 + aslot] = bv;
        }
        #pragma unroll
        for (int j = 0; j < 8; ++j) {
            int chunk = w * 8 + j;
            int col = chunk * 8 + bsrow;
            gll16(Bt + (size_t)col * 512 + ks + bscol, &Bs[chunk * 512]);
        }
        __syncthreads();

        #pragma unroll
        for (int kk = 0; kk < 2; ++kk) {
            bf16x8 a[4], b[4];
            #pragma unroll
            for (int mi = 0; mi < 4; ++mi) {
                int r = mi * 16 + l15;
                int slot = (kk * 4 + lg) ^ (r & 7);
                a[mi] = *(const bf16x8*)&As[r * 64 + slot * 8];
            }
            #pragma unroll
            for (int ni = 0; ni < 4; ++ni) {
                int r = w * 64 + ni * 16 + l15;
                int slot = (kk * 4 + lg) ^ (r & 7);
                b[ni] = *(const bf16x8*)&Bs[r * 64 + slot * 8];
            }
            #pragma unroll
            for (int mi = 0; mi < 4; ++mi)
                #pragma unroll
                for (int ni = 0; ni < 4; ++ni)
                    acc[mi][ni] = mfma16(a[mi], b[ni], acc[mi][ni]);
        }

        if (ki < 7) {
            va0 = *(const float4*)(xrow_p + (ki + 1) * 64);
            va1 = *(const float4*)(xrow_p + (ki + 1) * 64 + 4);
        }
        __syncthreads();
    }

    // epilogue constants through dead LDS (single, race-free write: As = exactly 512 float4)
    {
        float4 cp;
        cp.x = bq2[tid];
        cp.y = R[tid];
        cp.z = R[512 + tid];
        cp.w = R[1024 + tid];
        ((float4*)As)[tid] = cp;
    }
    if (tid < 64) {
        ((float*)Bs)[tid * 3 + 0] = rel[(size_t)(row0 + tid) * 3 + 0];
        ((float*)Bs)[tid * 3 + 1] = rel[(size_t)(row0 + tid) * 3 + 1];
        ((float*)Bs)[tid * 3 + 2] = rel[(size_t)(row0 + tid) * 3 + 2];
    }
    __syncthreads();

    #pragma unroll
    for (int mi = 0; mi < 4; ++mi) {
        float rl[4][3];
        #pragma unroll
        for (int r = 0; r < 4; ++r) {
            int rowL = mi * 16 + lg * 4 + r;
            rl[r][0] = ((const float*)Bs)[rowL * 3 + 0];
            rl[r][1] = ((const float*)Bs)[rowL * 3 + 1];
            rl[r][2] = ((const float*)Bs)[rowL * 3 + 2];
        }
        #pragma unroll
        for (int ni = 0; ni < 4; ++ni) {
            int col = w * 64 + ni * 16 + l15;
            float4 cp = ((const float4*)As)[col];
            #pragma unroll
            for (int r = 0; r < 4; ++r) {
                int rowL = mi * 16 + lg * 4 + r;
                float vv = acc[mi][ni][r] + cp.x
                         + rl[r][0] * cp.y + rl[r][1] * cp.z + rl[r][2] * cp.w;
                Qout[(size_t)(row0 + rowL) * 512 + col] = (bf16)vv;
            }
        }
    }
}

// ---------------- K4: proj GEMM — 8-phase m201-style, 256x256 tile, BK=64 ----------------
// (R11-proven). 8 waves (2Mx4N), per-wave 128x64 out, LDS 128KB, region-major layouts,
// counted vmcnt(6) steady-state, sched-fenced, setprio around MFMA.
__global__ __launch_bounds__(512, 2) void pgemm8(
    const bf16* __restrict__ A, const bf16* __restrict__ Bt,
    const float* __restrict__ bias, float* __restrict__ out)
{
    const int bid = blockIdx.x;                  // 1024
    const int wg = (bid & 7) * 128 + (bid >> 3); // bijective XCD swizzle
    const int ct = wg & 1, rt = wg >> 1;
    const int row0 = rt * 256, col0 = ct * 256;
    const int tid = threadIdx.x;
    const int w = tid >> 6, l = tid & 63;
    const int wr = w >> 2, wcol = w & 3;
    const int l15 = l & 15, lg = l >> 4;

    __shared__ __align__(16) bf16 Ab[2][16384];  // 2 x 32 KB
    __shared__ __align__(16) bf16 Bb[2][16384];

    f32x4 acc[8][4] = {};

    const int srr = w * 8 + (l >> 3);            // 0..63 per 64-row round
    const int sk  = ((l & 7) ^ (l >> 3)) << 3;   // pre-swizzled k element offset

    auto stageA = [&](int kt, int qm) {
        bf16* dst = &Ab[kt & 1][(qm * 128 + srr) * 64];
        int ks = kt * 64;
        gll16(A + (size_t)(row0 + qm * 64 + srr) * 512 + ks + sk, dst);
        gll16(A + (size_t)(row0 + 128 + qm * 64 + srr) * 512 + ks + sk, dst + 4096);
    };
    auto stageB = [&](int kt, int qn) {
        bf16* dst = &Bb[kt & 1][(qn * 128 + srr) * 64];
        int ks = kt * 64;
        int gc0 = (srr >> 5) * 64 + qn * 32 + (srr & 31);
        int rr1 = 64 + srr;
        int gc1 = (rr1 >> 5) * 64 + qn * 32 + (rr1 & 31);
        gll16(Bt + (size_t)(col0 + gc0) * 512 + ks + sk, dst);
        gll16(Bt + (size_t)(col0 + gc1) * 512 + ks + sk, dst + 4096);
    };

    stageA(0, 0); stageB(0, 0);
    SCHED_FENCE();
    stageA(0, 1); stageB(0, 1);
    SCHED_FENCE();
    stageA(1, 0); stageB(1, 0);
    SCHED_FENCE();

    #pragma unroll 1
    for (int kt = 0; kt < 8; ++kt) {
        const bf16* Ac = Ab[kt & 1];
        const bf16* Bc = Bb[kt & 1];
        #pragma unroll
        for (int q = 0; q < 4; ++q) {
            const int qm = q >> 1, qn = q & 1;
            bf16x8 a[4][2], b[2][2];

            if (q == 0) {
                SCHED_FENCE();
                if (kt < 7) stageA(kt + 1, 1);
                SCHED_FENCE();
                if (kt < 7) asm volatile("s_waitcnt vmcnt(6)" ::: "memory");
                else        asm volatile("s_waitcnt vmcnt(0)" ::: "memory");
                SCHED_FENCE();
                __builtin_amdgcn_s_barrier();
                SCHED_FENCE();
                #pragma unroll
                for (int miq = 0; miq < 4; ++miq) {
                    int lr = qm * 128 + wr * 64 + miq * 16 + l15;
                    #pragma unroll
                    for (int kk = 0; kk < 2; ++kk) {
                        int slot = (kk * 4 + lg) ^ (lr & 7);
                        a[miq][kk] = *(const bf16x8*)&Ac[lr * 64 + slot * 8];
                    }
                }
                #pragma unroll
                for (int njq = 0; njq < 2; ++njq) {
                    int lr = qn * 128 + wcol * 32 + njq * 16 + l15;
                    #pragma unroll
                    for (int kk = 0; kk < 2; ++kk) {
                        int slot = (kk * 4 + lg) ^ (lr & 7);
                        b[njq][kk] = *(const bf16x8*)&Bc[lr * 64 + slot * 8];
                    }
                }
            } else {
                #pragma unroll
                for (int miq = 0; miq < 4; ++miq) {
                    int lr = qm * 128 + wr * 64 + miq * 16 + l15;
                    #pragma unroll
                    for (int kk = 0; kk < 2; ++kk) {
                        int slot = (kk * 4 + lg) ^ (lr & 7);
                        a[miq][kk] = *(const bf16x8*)&Ac[lr * 64 + slot * 8];
                    }
                }
                #pragma unroll
                for (int njq = 0; njq < 2; ++njq) {
                    int lr = qn * 128 + wcol * 32 + njq * 16 + l15;
                    #pragma unroll
                    for (int kk = 0; kk < 2; ++kk) {
                        int slot = (kk * 4 + lg) ^ (lr & 7);
                        b[njq][kk] = *(const bf16x8*)&Bc[lr * 64 + slot * 8];
                    }
                }
                SCHED_FENCE();
                if (q == 1) { if (kt < 7) stageB(kt + 1, 1); }
                else if (q == 2) { if (kt < 6) stageA(kt + 2, 0); }
                else { if (kt < 6) stageB(kt + 2, 0); }
                SCHED_FENCE();
                __builtin_amdgcn_s_barrier();
            }

            asm volatile("s_waitcnt lgkmcnt(0)" ::: "memory");
            SCHED_FENCE();
            __builtin_amdgcn_s_setprio(1);
            #pragma unroll
            for (int miq = 0; miq < 4; ++miq)
                #pragma unroll
                for (int njq = 0; njq < 2; ++njq)
                    #pragma unroll
                    for (int kk = 0; kk < 2; ++kk)
                        acc[qm * 4 + miq][qn * 2 + njq] =
                            mfma16(a[miq][kk], b[njq][kk], acc[qm * 4 + miq][qn * 2 + njq]);
            __builtin_amdgcn_s_setprio(0);
            SCHED_FENCE();
            __builtin_amdgcn_s_barrier();
        }
    }
    SCHED_FENCE();

    #pragma unroll
    for (int ni = 0; ni < 4; ++ni) {
        int col = col0 + wcol * 64 + ni * 16 + l15;
        float bv = bias[col];
        #pragma unroll
        for (int mi = 0; mi < 8; ++mi) {
            size_t rbase = (size_t)row0 + wr * 128 + mi * 16 + lg * 4;
            #pragma unroll
            for (int r = 0; r < 4; ++r)
                out[(rbase + r) * 512 + col] = acc[mi][ni][r] + bv;
        }
    }
}

// ---------------- K2: k_sel / v_selT (x' recomputed inline for 1024 tokens) ----------------
__global__ __launch_bounds__(256) void kv_proj2(
    const float* __restrict__ x, const float* __restrict__ rel,
    const float* __restrict__ pe_w, const float* __restrict__ pe_b,
    const bf16* __restrict__ kvWT, const float* __restrict__ bkv,
    bf16* __restrict__ ksel, bf16* __restrict__ vselT)
{
    const int bid = blockIdx.x;
    const int b = bid >> 9;
    const int ball = (bid >> 6) & 7;
    const int m2 = bid & 63;
    const size_t tok = (size_t)b * 65536 + ball * 64 + m2;
    const int tid = threadIdx.x;

    __shared__ __align__(16) bf16 xrow[512];
    __shared__ float relt[3];
    if (tid < 3) relt[tid] = rel[tok * 3 + tid];
    __syncthreads();
    for (int k = tid; k < 512; k += 256) {
        float v = x[tok * 512 + k] + relt[0] * pe_w[k] + relt[1] * pe_w[512 + k]
                + relt[2] * pe_w[1024 + k] + pe_b[k];
        xrow[k] = (bf16)v;
    }
    __syncthreads();

    float acc = 0.f;
    const bf16* wrp = kvWT + (size_t)tid * 512;
    #pragma unroll 8
    for (int k = 0; k < 512; k += 8) {
        bf16x8 wv = *(const bf16x8*)(wrp + k);
        bf16x8 xv = *(const bf16x8*)(&xrow[k]);
        #pragma unroll
        for (int j = 0; j < 8; ++j) acc += (float)xv[j] * (float)wv[j];
    }
    acc += bkv[tid];
    int t = tid >> 7, kk = (tid >> 6) & 1, e = tid & 63;
    if (kk == 0)
        ksel[((size_t)(b * 8 + ball) * 128 + t * 64 + m2) * 64 + e] = (bf16)acc;
    else
        vselT[((size_t)(b * 8 + ball) * 64 + e) * 128 + t * 64 + m2] = (bf16)acc;
}

// ---------------- K3: attention, 16 q-tiles per block (K/V staged once) ----------------
__global__ __launch_bounds__(256) void attn16(
    const bf16* __restrict__ q, const bf16* __restrict__ ksel,
    const bf16* __restrict__ vselT, bf16* __restrict__ attno)
{
    const int bid = blockIdx.x;      // 1024 = 16 bh * 64 qgroups
    const int qg = bid & 63;
    const int bh = bid >> 6;
    const int b = bh >> 3;
    const int h = bh & 7;
    const int tid = threadIdx.x;
    const int w = tid >> 6;
    const int l = tid & 63;
    const int l15 = l & 15, lg = l >> 4;

    __shared__ __align__(16) bf16 Ks[128][72];
    __shared__ __align__(16) bf16 Vt[64][136];
    __shared__ __align__(16) bf16 Pl[4][16][136];

    const bf16* kg = ksel + (size_t)(b * 8 + h) * 128 * 64;
    #pragma unroll
    for (int it = 0; it < 4; ++it) {
        int i = it * 256 + tid;
        int r = i >> 3, c8 = (i & 7) * 8;
        *(bf16x8*)&Ks[r][c8] = *(const bf16x8*)(kg + r * 64 + c8);
    }
    const bf16* vg = vselT + (size_t)(b * 8 + h) * 64 * 128;
    #pragma unroll
    for (int it = 0; it < 4; ++it) {
        int i = it * 256 + tid;
        int r = i >> 4, c8 = (i & 15) * 8;
        *(bf16x8*)&Vt[r][c8] = *(const bf16x8*)(vg + r * 128 + c8);
    }
    __syncthreads();

    for (int qi = 0; qi < 16; ++qi) {
        const int qt = qg * 16 + qi;
        const size_t tokq = (size_t)b * 65536 + (size_t)qt * 64 + w * 16 + l15;
        const bf16* qp = q + tokq * 512 + h * 64 + lg * 8;
        bf16x8 qa0 = *(const bf16x8*)qp;
        bf16x8 qa1 = *(const bf16x8*)(qp + 32);

        f32x4 s[8];
        #pragma unroll
        for (int kt = 0; kt < 8; ++kt) {
            f32x4 a0 = {0.f, 0.f, 0.f, 0.f};
            a0 = mfma16(qa0, *(const bf16x8*)&Ks[kt * 16 + l15][lg * 8], a0);
            a0 = mfma16(qa1, *(const bf16x8*)&Ks[kt * 16 + l15][32 + lg * 8], a0);
            s[kt] = a0;
        }

        #pragma unroll
        for (int r = 0; r < 4; ++r) {
            float mx = s[0][r];
            #pragma unroll
            for (int kt = 1; kt < 8; ++kt) mx = fmaxf(mx, s[kt][r]);
            mx = fmaxf(mx, __shfl_xor(mx, 1));
            mx = fmaxf(mx, __shfl_xor(mx, 2));
            mx = fmaxf(mx, __shfl_xor(mx, 4));
            mx = fmaxf(mx, __shfl_xor(mx, 8));
            float sum = 0.f;
            #pragma unroll
            for (int kt = 0; kt < 8; ++kt) {
                float p = __expf(s[kt][r] - mx);
                s[kt][r] = p;
                sum += p;
            }
            sum += __shfl_xor(sum, 1);
            sum += __shfl_xor(sum, 2);
            sum += __shfl_xor(sum, 4);
            sum += __shfl_xor(sum, 8);
            float inv = 1.0f / sum;
            int prow = lg * 4 + r;
            #pragma unroll
            for (int kt = 0; kt < 8; ++kt)
                Pl[w][prow][kt * 16 + l15] = (bf16)(s[kt][r] * inv);
        }

        f32x4 o[4] = { {0,0,0,0}, {0,0,0,0}, {0,0,0,0}, {0,0,0,0} };
        #pragma unroll
        for (int kc = 0; kc < 4; ++kc) {
            bf16x8 pa = *(const bf16x8*)&Pl[w][l15][kc * 32 + lg * 8];
            #pragma unroll
            for (int et = 0; et < 4; ++et)
                o[et] = mfma16(pa, *(const bf16x8*)&Vt[et * 16 + l15][kc * 32 + lg * 8], o[et]);
        }

        #pragma unroll
        for (int et = 0; et < 4; ++et)
            #pragma unroll
            for (int r = 0; r < 4; ++r)
                Pl[w][lg * 4 + r][et * 16 + l15] = (bf16)(o[et][r]);

        __syncthreads();
        {
            int rowg = tid >> 2;
            int w2 = rowg >> 4, lr = rowg & 15;
            int chunk = tid & 3;
            const size_t tok = (size_t)b * 65536 + (size_t)qt * 64 + rowg;
            bf16* gp = attno + tok * 512 + h * 64 + chunk * 16;
            const bf16* lp = &Pl[w2][lr][chunk * 16];
            *(bf16x8*)(gp + 0) = *(const bf16x8*)(lp + 0);
            *(bf16x8*)(gp + 8) = *(const bf16x8*)(lp + 8);
        }
        __syncthreads();
    }
}

extern "C" void kernel_launch(void* const* d_in, const int* in_sizes, int n_in,
                              void* d_out, int out_size, void* d_ws, size_t ws_size,
                              hipStream_t stream) {
    (void)in_sizes; (void)n_in; (void)out_size; (void)ws_size;
    const float* x      = (const float*)d_in[0];
    const float* pos    = (const float*)d_in[1];
    const float* qkv_w  = (const float*)d_in[2];
    const float* qkv_b  = (const float*)d_in[3];
    const float* proj_w = (const float*)d_in[4];
    const float* proj_b = (const float*)d_in[5];
    const float* pe_w   = (const float*)d_in[6];
    const float* pe_b   = (const float*)d_in[7];

    char* ws = (char*)d_ws;
    bf16*  Q     = (bf16*)(ws);                          // 134217728
    bf16*  Z     = (bf16*)(ws + 134217728);              // 134217728 (attn out)
    bf16*  BqT   = (bf16*)(ws + 268435456);              // 524288
    bf16*  PjT   = (bf16*)(ws + 268959744);              // 524288
    bf16*  kvWT  = (bf16*)(ws + 269484032);              // 262144
    bf16*  ksel  = (bf16*)(ws + 269746176);              // 262144
    bf16*  vselT = (bf16*)(ws + 270008320);              // 262144
    float* rel   = (float*)(ws + 270270464);             // 1572864
    float* R     = (float*)(ws + 271843328);             // 6144
    float* bq2   = (float*)(ws + 271849472);             // 2048
    float* bkv   = (float*)(ws + 271851520);             // 1024

    prep_weights<<<2561, 256, 0, stream>>>(qkv_w, qkv_b, proj_w, BqT, kvWT, PjT, bkv);
    prep_r2<<<512, 256, 0, stream>>>(qkv_w, qkv_b, pe_w, pe_b, R, bq2);
    relprep<<<2048, 64, 0, stream>>>(pos, rel);
    qgemm6<<<2048, 512, 0, stream>>>(x, BqT, rel, R, bq2, Q);
    kv_proj2<<<1024, 256, 0, stream>>>(x, rel, pe_w, pe_b, kvWT, bkv, ksel, vselT);
    attn16<<<1024, 256, 0, stream>>>(Q, ksel, vselT, Z);
    pgemm8<<<1024, 512, 0, stream>>>(Z, PjT, proj_b, (float*)d_out);
}

// Round 14
// 410.412 us; speedup vs baseline: 1.4321x; 1.0467x over previous
//
#include <hip/hip_runtime.h>

typedef __bf16 bf16;
typedef __bf16 bf16x8 __attribute__((ext_vector_type(8)));
typedef __bf16 bf16x4 __attribute__((ext_vector_type(4)));
typedef float  f32x4  __attribute__((ext_vector_type(4)));

__device__ __forceinline__ f32x4 mfma16(bf16x8 a, bf16x8 b, f32x4 c) {
    return __builtin_amdgcn_mfma_f32_16x16x32_bf16(a, b, c, 0, 0, 0);
}

__device__ __forceinline__ void gll16(const bf16* g, bf16* l) {
    __builtin_amdgcn_global_load_lds(
        (const __attribute__((address_space(1))) void*)g,
        (__attribute__((address_space(3))) void*)l, 16, 0, 0);
}

#define SCHED_FENCE() __builtin_amdgcn_sched_barrier(0)

// ---------------- K0: weight repack (BqT scaled+deinterleaved, kvWT, projT) ----------------
__global__ __launch_bounds__(256) void prep_weights(
    const float* __restrict__ qkv_w, const float* __restrict__ qkv_b,
    const float* __restrict__ proj_w,
    bf16* __restrict__ BqT, bf16* __restrict__ kvWT, bf16* __restrict__ projWT,
    float* __restrict__ bkv)
{
    int i = blockIdx.x * 256 + threadIdx.x;
    if (i < 262144) {
        int c_ = i >> 9, k = i & 511;
        int c = (c_ >> 6) * 192 + (c_ & 63) * 3;
        BqT[i] = (bf16)(qkv_w[k * 1536 + c] * 0.125f);
        return;
    }
    i -= 262144;
    if (i < 131072) {
        int c2 = i >> 9, k = i & 511;
        int t = c2 >> 7, kk = (c2 >> 6) & 1, e = c2 & 63;
        int c = t * 192 + e * 3 + 1 + kk;
        kvWT[i] = (bf16)(qkv_w[k * 1536 + c]);
        return;
    }
    i -= 131072;
    if (i < 262144) {
        int c_ = i >> 9, k = i & 511;
        projWT[i] = (bf16)(proj_w[k * 512 + c_]);
        return;
    }
    i -= 262144;
    if (i < 256) {
        int t = i >> 7, kk = (i >> 6) & 1, e = i & 63;
        bkv[i] = qkv_b[t * 192 + e * 3 + 1 + kk];
    }
}

// ---------------- K0b: R = pe_w @ Wq_scaled [3][512], bq2 — block-parallel reduce ----------------
__global__ __launch_bounds__(256) void prep_r2(
    const float* __restrict__ qkv_w, const float* __restrict__ qkv_b,
    const float* __restrict__ pe_w, const float* __restrict__ pe_b,
    float* __restrict__ R, float* __restrict__ bq2)
{
    const int c = blockIdx.x;            // 512
    const int tid = threadIdx.x;
    const int qc = (c >> 6) * 192 + (c & 63) * 3;
    float p0 = 0.f, p1 = 0.f, p2 = 0.f, p3 = 0.f;
    for (int k = tid; k < 512; k += 256) {
        float wv = qkv_w[(size_t)k * 1536 + qc];
        p0 += wv * pe_w[k];
        p1 += wv * pe_w[512 + k];
        p2 += wv * pe_w[1024 + k];
        p3 += wv * pe_b[k];
    }
    #pragma unroll
    for (int m = 1; m < 64; m <<= 1) {
        p0 += __shfl_xor(p0, m);
        p1 += __shfl_xor(p1, m);
        p2 += __shfl_xor(p2, m);
        p3 += __shfl_xor(p3, m);
    }
    __shared__ float red[4][4];
    int w = tid >> 6;
    if ((tid & 63) == 0) { red[w][0] = p0; red[w][1] = p1; red[w][2] = p2; red[w][3] = p3; }
    __syncthreads();
    if (tid == 0) {
        float s0 = red[0][0] + red[1][0] + red[2][0] + red[3][0];
        float s1 = red[0][1] + red[1][1] + red[2][1] + red[3][1];
        float s2 = red[0][2] + red[1][2] + red[2][2] + red[3][2];
        float s3 = red[0][3] + red[1][3] + red[2][3] + red[3][3];
        R[0 * 512 + c] = 0.125f * s0;
        R[1 * 512 + c] = 0.125f * s1;
        R[2 * 512 + c] = 0.125f * s2;
        bq2[c] = 0.125f * (qkv_b[qc] + s3);
    }
}

// ---------------- K0c: rel[t][3] = pos - ball mean ----------------
__global__ __launch_bounds__(64) void relprep(const float* __restrict__ pos,
                                              float* __restrict__ rel)
{
    const int t = blockIdx.x * 64 + threadIdx.x;
    float p0 = pos[(size_t)t * 3 + 0];
    float p1 = pos[(size_t)t * 3 + 1];
    float p2 = pos[(size_t)t * 3 + 2];
    float s0 = p0, s1 = p1, s2 = p2;
    #pragma unroll
    for (int m = 1; m < 64; m <<= 1) {
        s0 += __shfl_xor(s0, m);
        s1 += __shfl_xor(s1, m);
        s2 += __shfl_xor(s2, m);
    }
    rel[(size_t)t * 3 + 0] = p0 - s0 * (1.0f / 64.0f);
    rel[(size_t)t * 3 + 1] = p1 - s1 * (1.0f / 64.0f);
    rel[(size_t)t * 3 + 2] = p2 - s2 * (1.0f / 64.0f);
}

// ---------------- K1: Q = bf16(x') @ BqT^T — FULL-N block (64 rows x 512 cols) ----------------
// 8 waves; wave w owns cols [w*64, w*64+64). A read ONCE per row; B via gll16 (L2-hot).
__global__ __launch_bounds__(512) void qgemm6(
    const float* __restrict__ X, const bf16* __restrict__ Bt,
    const float* __restrict__ rel, const float* __restrict__ R,
    const float* __restrict__ bq2, bf16* __restrict__ Qout)
{
    const int row0 = blockIdx.x * 64;
    const int tid = threadIdx.x;
    const int w = tid >> 6, l = tid & 63;
    const int l15 = l & 15, lg = l >> 4;

    __shared__ __align__(16) bf16 As[4096];      // 64 rows x 64 k (swizzled)
    __shared__ __align__(16) bf16 Bs[32768];     // 512 cols x 64 k (swizzled)

    f32x4 acc[4][4] = {};

    const int arow = tid >> 3;
    const int aslot = ((tid & 7) ^ (arow & 7)) << 3;
    const float* xrow_p = X + (size_t)(row0 + arow) * 512 + (tid & 7) * 8;

    const int bsrow = l >> 3;
    const int bscol = (((l & 7) ^ (l >> 3)) << 3);

    float4 va0 = *(const float4*)xrow_p;
    float4 va1 = *(const float4*)(xrow_p + 4);

    for (int ki = 0; ki < 8; ++ki) {
        int ks = ki * 64;
        {
            bf16x8 bv = { (bf16)va0.x, (bf16)va0.y, (bf16)va0.z, (bf16)va0.w,
                          (bf16)va1.x, (bf16)va1.y, (bf16)va1.z, (bf16)va1.w };
            *(bf16x8*)&As[arow * 64 + aslot] = bv;
        }
        #pragma unroll
        for (int j = 0; j < 8; ++j) {
            int chunk = w * 8 + j;
            int col = chunk * 8 + bsrow;
            gll16(Bt + (size_t)col * 512 + ks + bscol, &Bs[chunk * 512]);
        }
        __syncthreads();

        #pragma unroll
        for (int kk = 0; kk < 2; ++kk) {
            bf16x8 a[4], b[4];
            #pragma unroll
            for (int mi = 0; mi < 4; ++mi) {
                int r = mi * 16 + l15;
                int slot = (kk * 4 + lg) ^ (r & 7);
                a[mi] = *(const bf16x8*)&As[r * 64 + slot * 8];
            }
            #pragma unroll
            for (int ni = 0; ni < 4; ++ni) {
                int r = w * 64 + ni * 16 + l15;
                int slot = (kk * 4 + lg) ^ (r & 7);
                b[ni] = *(const bf16x8*)&Bs[r * 64 + slot * 8];
            }
            #pragma unroll
            for (int mi = 0; mi < 4; ++mi)
                #pragma unroll
                for (int ni = 0; ni < 4; ++ni)
                    acc[mi][ni] = mfma16(a[mi], b[ni], acc[mi][ni]);
        }

        if (ki < 7) {
            va0 = *(const float4*)(xrow_p + (ki + 1) * 64);
            va1 = *(const float4*)(xrow_p + (ki + 1) * 64 + 4);
        }
        __syncthreads();
    }

    // epilogue constants through dead LDS (single, race-free write: As = exactly 512 float4)
    {
        float4 cp;
        cp.x = bq2[tid];
        cp.y = R[tid];
        cp.z = R[512 + tid];
        cp.w = R[1024 + tid];
        ((float4*)As)[tid] = cp;
    }
    if (tid < 64) {
        ((float*)Bs)[tid * 3 + 0] = rel[(size_t)(row0 + tid) * 3 + 0];
        ((float*)Bs)[tid * 3 + 1] = rel[(size_t)(row0 + tid) * 3 + 1];
        ((float*)Bs)[tid * 3 + 2] = rel[(size_t)(row0 + tid) * 3 + 2];
    }
    __syncthreads();

    #pragma unroll
    for (int mi = 0; mi < 4; ++mi) {
        float rl[4][3];
        #pragma unroll
        for (int r = 0; r < 4; ++r) {
            int rowL = mi * 16 + lg * 4 + r;
            rl[r][0] = ((const float*)Bs)[rowL * 3 + 0];
            rl[r][1] = ((const float*)Bs)[rowL * 3 + 1];
            rl[r][2] = ((const float*)Bs)[rowL * 3 + 2];
        }
        #pragma unroll
        for (int ni = 0; ni < 4; ++ni) {
            int col = w * 64 + ni * 16 + l15;
            float4 cp = ((const float4*)As)[col];
            #pragma unroll
            for (int r = 0; r < 4; ++r) {
                int rowL = mi * 16 + lg * 4 + r;
                float vv = acc[mi][ni][r] + cp.x
                         + rl[r][0] * cp.y + rl[r][1] * cp.z + rl[r][2] * cp.w;
                Qout[(size_t)(row0 + rowL) * 512 + col] = (bf16)vv;
            }
        }
    }
}

// ---------------- K4: proj GEMM — 8-phase, 256x256 tile, BK=64 (R11-proven) ----------------
__global__ __launch_bounds__(512, 2) void pgemm8(
    const bf16* __restrict__ A, const bf16* __restrict__ Bt,
    const float* __restrict__ bias, float* __restrict__ out)
{
    const int bid = blockIdx.x;                  // 1024
    const int wg = (bid & 7) * 128 + (bid >> 3); // bijective XCD swizzle
    const int ct = wg & 1, rt = wg >> 1;
    const int row0 = rt * 256, col0 = ct * 256;
    const int tid = threadIdx.x;
    const int w = tid >> 6, l = tid & 63;
    const int wr = w >> 2, wcol = w & 3;
    const int l15 = l & 15, lg = l >> 4;

    __shared__ __align__(16) bf16 Ab[2][16384];  // 2 x 32 KB
    __shared__ __align__(16) bf16 Bb[2][16384];

    f32x4 acc[8][4] = {};

    const int srr = w * 8 + (l >> 3);            // 0..63 per 64-row round
    const int sk  = ((l & 7) ^ (l >> 3)) << 3;   // pre-swizzled k element offset

    auto stageA = [&](int kt, int qm) {
        bf16* dst = &Ab[kt & 1][(qm * 128 + srr) * 64];
        int ks = kt * 64;
        gll16(A + (size_t)(row0 + qm * 64 + srr) * 512 + ks + sk, dst);
        gll16(A + (size_t)(row0 + 128 + qm * 64 + srr) * 512 + ks + sk, dst + 4096);
    };
    auto stageB = [&](int kt, int qn) {
        bf16* dst = &Bb[kt & 1][(qn * 128 + srr) * 64];
        int ks = kt * 64;
        int gc0 = (srr >> 5) * 64 + qn * 32 + (srr & 31);
        int rr1 = 64 + srr;
        int gc1 = (rr1 >> 5) * 64 + qn * 32 + (rr1 & 31);
        gll16(Bt + (size_t)(col0 + gc0) * 512 + ks + sk, dst);
        gll16(Bt + (size_t)(col0 + gc1) * 512 + ks + sk, dst + 4096);
    };

    stageA(0, 0); stageB(0, 0);
    SCHED_FENCE();
    stageA(0, 1); stageB(0, 1);
    SCHED_FENCE();
    stageA(1, 0); stageB(1, 0);
    SCHED_FENCE();

    #pragma unroll 1
    for (int kt = 0; kt < 8; ++kt) {
        const bf16* Ac = Ab[kt & 1];
        const bf16* Bc = Bb[kt & 1];
        #pragma unroll
        for (int q = 0; q < 4; ++q) {
            const int qm = q >> 1, qn = q & 1;
            bf16x8 a[4][2], b[2][2];

            if (q == 0) {
                SCHED_FENCE();
                if (kt < 7) stageA(kt + 1, 1);
                SCHED_FENCE();
                if (kt < 7) asm volatile("s_waitcnt vmcnt(6)" ::: "memory");
                else        asm volatile("s_waitcnt vmcnt(0)" ::: "memory");
                SCHED_FENCE();
                __builtin_amdgcn_s_barrier();
                SCHED_FENCE();
                #pragma unroll
                for (int miq = 0; miq < 4; ++miq) {
                    int lr = qm * 128 + wr * 64 + miq * 16 + l15;
                    #pragma unroll
                    for (int kk = 0; kk < 2; ++kk) {
                        int slot = (kk * 4 + lg) ^ (lr & 7);
                        a[miq][kk] = *(const bf16x8*)&Ac[lr * 64 + slot * 8];
                    }
                }
                #pragma unroll
                for (int njq = 0; njq < 2; ++njq) {
                    int lr = qn * 128 + wcol * 32 + njq * 16 + l15;
                    #pragma unroll
                    for (int kk = 0; kk < 2; ++kk) {
                        int slot = (kk * 4 + lg) ^ (lr & 7);
                        b[njq][kk] = *(const bf16x8*)&Bc[lr * 64 + slot * 8];
                    }
                }
            } else {
                #pragma unroll
                for (int miq = 0; miq < 4; ++miq) {
                    int lr = qm * 128 + wr * 64 + miq * 16 + l15;
                    #pragma unroll
                    for (int kk = 0; kk < 2; ++kk) {
                        int slot = (kk * 4 + lg) ^ (lr & 7);
                        a[miq][kk] = *(const bf16x8*)&Ac[lr * 64 + slot * 8];
                    }
                }
                #pragma unroll
                for (int njq = 0; njq < 2; ++njq) {
                    int lr = qn * 128 + wcol * 32 + njq * 16 + l15;
                    #pragma unroll
                    for (int kk = 0; kk < 2; ++kk) {
                        int slot = (kk * 4 + lg) ^ (lr & 7);
                        b[njq][kk] = *(const bf16x8*)&Bc[lr * 64 + slot * 8];
                    }
                }
                SCHED_FENCE();
                if (q == 1) { if (kt < 7) stageB(kt + 1, 1); }
                else if (q == 2) { if (kt < 6) stageA(kt + 2, 0); }
                else { if (kt < 6) stageB(kt + 2, 0); }
                SCHED_FENCE();
                __builtin_amdgcn_s_barrier();
            }

            asm volatile("s_waitcnt lgkmcnt(0)" ::: "memory");
            SCHED_FENCE();
            __builtin_amdgcn_s_setprio(1);
            #pragma unroll
            for (int miq = 0; miq < 4; ++miq)
                #pragma unroll
                for (int njq = 0; njq < 2; ++njq)
                    #pragma unroll
                    for (int kk = 0; kk < 2; ++kk)
                        acc[qm * 4 + miq][qn * 2 + njq] =
                            mfma16(a[miq][kk], b[njq][kk], acc[qm * 4 + miq][qn * 2 + njq]);
            __builtin_amdgcn_s_setprio(0);
            SCHED_FENCE();
            __builtin_amdgcn_s_barrier();
        }
    }
    SCHED_FENCE();

    #pragma unroll
    for (int ni = 0; ni < 4; ++ni) {
        int col = col0 + wcol * 64 + ni * 16 + l15;
        float bv = bias[col];
        #pragma unroll
        for (int mi = 0; mi < 8; ++mi) {
            size_t rbase = (size_t)row0 + wr * 128 + mi * 16 + lg * 4;
            #pragma unroll
            for (int r = 0; r < 4; ++r)
                out[(rbase + r) * 512 + col] = acc[mi][ni][r] + bv;
        }
    }
}

// ---------------- K2: k_sel / v_selT (x' recomputed inline for 1024 tokens) ----------------
__global__ __launch_bounds__(256) void kv_proj2(
    const float* __restrict__ x, const float* __restrict__ rel,
    const float* __restrict__ pe_w, const float* __restrict__ pe_b,
    const bf16* __restrict__ kvWT, const float* __restrict__ bkv,
    bf16* __restrict__ ksel, bf16* __restrict__ vselT)
{
    const int bid = blockIdx.x;
    const int b = bid >> 9;
    const int ball = (bid >> 6) & 7;
    const int m2 = bid & 63;
    const size_t tok = (size_t)b * 65536 + ball * 64 + m2;
    const int tid = threadIdx.x;

    __shared__ __align__(16) bf16 xrow[512];
    __shared__ float relt[3];
    if (tid < 3) relt[tid] = rel[tok * 3 + tid];
    __syncthreads();
    for (int k = tid; k < 512; k += 256) {
        float v = x[tok * 512 + k] + relt[0] * pe_w[k] + relt[1] * pe_w[512 + k]
                + relt[2] * pe_w[1024 + k] + pe_b[k];
        xrow[k] = (bf16)v;
    }
    __syncthreads();

    float acc = 0.f;
    const bf16* wrp = kvWT + (size_t)tid * 512;
    #pragma unroll 8
    for (int k = 0; k < 512; k += 8) {
        bf16x8 wv = *(const bf16x8*)(wrp + k);
        bf16x8 xv = *(const bf16x8*)(&xrow[k]);
        #pragma unroll
        for (int j = 0; j < 8; ++j) acc += (float)xv[j] * (float)wv[j];
    }
    acc += bkv[tid];
    int t = tid >> 7, kk = (tid >> 6) & 1, e = tid & 63;
    if (kk == 0)
        ksel[((size_t)(b * 8 + ball) * 128 + t * 64 + m2) * 64 + e] = (bf16)acc;
    else
        vselT[((size_t)(b * 8 + ball) * 64 + e) * 128 + t * 64 + m2] = (bf16)acc;
}

// ---------------- K3: attention, 4 q-tiles per block (K/V staged once) ----------------
__global__ __launch_bounds__(256) void attn4(
    const bf16* __restrict__ q, const bf16* __restrict__ ksel,
    const bf16* __restrict__ vselT, bf16* __restrict__ attno)
{
    const int bid = blockIdx.x;      // 4096 = 16 bh * 256 qgroups
    const int qg = bid & 255;
    const int bh = bid >> 8;
    const int b = bh >> 3;
    const int h = bh & 7;
    const int tid = threadIdx.x;
    const int w = tid >> 6;
    const int l = tid & 63;
    const int l15 = l & 15, lg = l >> 4;

    __shared__ __align__(16) bf16 Ks[128][72];
    __shared__ __align__(16) bf16 Vt[64][136];
    __shared__ __align__(16) bf16 Pl[4][16][136];

    const bf16* kg = ksel + (size_t)(b * 8 + h) * 128 * 64;
    #pragma unroll
    for (int it = 0; it < 4; ++it) {
        int i = it * 256 + tid;
        int r = i >> 3, c8 = (i & 7) * 8;
        *(bf16x8*)&Ks[r][c8] = *(const bf16x8*)(kg + r * 64 + c8);
    }
    const bf16* vg = vselT + (size_t)(b * 8 + h) * 64 * 128;
    #pragma unroll
    for (int it = 0; it < 4; ++it) {
        int i = it * 256 + tid;
        int r = i >> 4, c8 = (i & 15) * 8;
        *(bf16x8*)&Vt[r][c8] = *(const bf16x8*)(vg + r * 128 + c8);
    }
    __syncthreads();

    for (int qi = 0; qi < 4; ++qi) {
        const int qt = qg * 4 + qi;
        const size_t tokq = (size_t)b * 65536 + (size_t)qt * 64 + w * 16 + l15;
        const bf16* qp = q + tokq * 512 + h * 64 + lg * 8;
        bf16x8 qa0 = *(const bf16x8*)qp;
        bf16x8 qa1 = *(const bf16x8*)(qp + 32);

        f32x4 s[8];
        #pragma unroll
        for (int kt = 0; kt < 8; ++kt) {
            f32x4 a0 = {0.f, 0.f, 0.f, 0.f};
            a0 = mfma16(qa0, *(const bf16x8*)&Ks[kt * 16 + l15][lg * 8], a0);
            a0 = mfma16(qa1, *(const bf16x8*)&Ks[kt * 16 + l15][32 + lg * 8], a0);
            s[kt] = a0;
        }

        #pragma unroll
        for (int r = 0; r < 4; ++r) {
            float mx = s[0][r];
            #pragma unroll
            for (int kt = 1; kt < 8; ++kt) mx = fmaxf(mx, s[kt][r]);
            mx = fmaxf(mx, __shfl_xor(mx, 1));
            mx = fmaxf(mx, __shfl_xor(mx, 2));
            mx = fmaxf(mx, __shfl_xor(mx, 4));
            mx = fmaxf(mx, __shfl_xor(mx, 8));
            float sum = 0.f;
            #pragma unroll
            for (int kt = 0; kt < 8; ++kt) {
                float p = __expf(s[kt][r] - mx);
                s[kt][r] = p;
                sum += p;
            }
            sum += __shfl_xor(sum, 1);
            sum += __shfl_xor(sum, 2);
            sum += __shfl_xor(sum, 4);
            sum += __shfl_xor(sum, 8);
            float inv = 1.0f / sum;
            int prow = lg * 4 + r;
            #pragma unroll
            for (int kt = 0; kt < 8; ++kt)
                Pl[w][prow][kt * 16 + l15] = (bf16)(s[kt][r] * inv);
        }

        f32x4 o[4] = { {0,0,0,0}, {0,0,0,0}, {0,0,0,0}, {0,0,0,0} };
        #pragma unroll
        for (int kc = 0; kc < 4; ++kc) {
            bf16x8 pa = *(const bf16x8*)&Pl[w][l15][kc * 32 + lg * 8];
            #pragma unroll
            for (int et = 0; et < 4; ++et)
                o[et] = mfma16(pa, *(const bf16x8*)&Vt[et * 16 + l15][kc * 32 + lg * 8], o[et]);
        }

        #pragma unroll
        for (int et = 0; et < 4; ++et)
            #pragma unroll
            for (int r = 0; r < 4; ++r)
                Pl[w][lg * 4 + r][et * 16 + l15] = (bf16)(o[et][r]);

        __syncthreads();
        {
            int rowg = tid >> 2;
            int w2 = rowg >> 4, lr = rowg & 15;
            int chunk = tid & 3;
            const size_t tok = (size_t)b * 65536 + (size_t)qt * 64 + rowg;
            bf16* gp = attno + tok * 512 + h * 64 + chunk * 16;
            const bf16* lp = &Pl[w2][lr][chunk * 16];
            *(bf16x8*)(gp + 0) = *(const bf16x8*)(lp + 0);
            *(bf16x8*)(gp + 8) = *(const bf16x8*)(lp + 8);
        }
        __syncthreads();
    }
}

extern "C" void kernel_launch(void* const* d_in, const int* in_sizes, int n_in,
                              void* d_out, int out_size, void* d_ws, size_t ws_size,
                              hipStream_t stream) {
    (void)in_sizes; (void)n_in; (void)out_size; (void)ws_size;
    const float* x      = (const float*)d_in[0];
    const float* pos    = (const float*)d_in[1];
    const float* qkv_w  = (const float*)d_in[2];
    const float* qkv_b  = (const float*)d_in[3];
    const float* proj_w = (const float*)d_in[4];
    const float* proj_b = (const float*)d_in[5];
    const float* pe_w   = (const float*)d_in[6];
    const float* pe_b   = (const float*)d_in[7];

    char* ws = (char*)d_ws;
    bf16*  Q     = (bf16*)(ws);                          // 134217728
    bf16*  Z     = (bf16*)(ws + 134217728);              // 134217728 (attn out)
    bf16*  BqT   = (bf16*)(ws + 268435456);              // 524288
    bf16*  PjT   = (bf16*)(ws + 268959744);              // 524288
    bf16*  kvWT  = (bf16*)(ws + 269484032);              // 262144
    bf16*  ksel  = (bf16*)(ws + 269746176);              // 262144
    bf16*  vselT = (bf16*)(ws + 270008320);              // 262144
    float* rel   = (float*)(ws + 270270464);             // 1572864
    float* R     = (float*)(ws + 271843328);             // 6144
    float* bq2   = (float*)(ws + 271849472);             // 2048
    float* bkv   = (float*)(ws + 271851520);             // 1024

    prep_weights<<<2561, 256, 0, stream>>>(qkv_w, qkv_b, proj_w, BqT, kvWT, PjT, bkv);
    prep_r2<<<512, 256, 0, stream>>>(qkv_w, qkv_b, pe_w, pe_b, R, bq2);
    relprep<<<2048, 64, 0, stream>>>(pos, rel);
    qgemm6<<<2048, 512, 0, stream>>>(x, BqT, rel, R, bq2, Q);
    kv_proj2<<<1024, 256, 0, stream>>>(x, rel, pe_w, pe_b, kvWT, bkv, ksel, vselT);
    attn4<<<4096, 256, 0, stream>>>(Q, ksel, vselT, Z);
    pgemm8<<<1024, 512, 0, stream>>>(Z, PjT, proj_b, (float*)d_out);
}